// Round 1
// baseline (105.631 us; speedup 1.0000x reference)
//
#include <hip/hip_runtime.h>

// HTSK fuzzy-TSK fused kernel for MI355X (gfx950).
// Reference: logits[b,r] = sum_i -(X[b,i]-C[i,r])^2 * S[i,r],  S = H/sig^2+EPS
//            frs = softmax(logits); out = [frs*X (rule-major), frs] @ W.T + b
// d_out = [out fp32 16384*32][frs fp32 16384*128]

#define H_CONST 0.5f
#define EPS_CONST 1e-8f
#define NROWS 16384
#define NRULES 128
#define WCOLS 8320

typedef _Float16 half8 __attribute__((ext_vector_type(8)));
typedef float floatx4 __attribute__((ext_vector_type(4)));

#define MFMA16(a, b, c) __builtin_amdgcn_mfma_f32_16x16x32_f16((a), (b), (c), 0, 0, 0)

// ws layout (halves):
//   Wfrag : [r 128][s 2][nt 2][L 64][j 8]          = 262144 halves (main GEMM B)
//   W0frag: [s 4][nt 2][L 64][j 8]                 =   4096 halves (frs @ W0 B)
//   Bmat  : [s 12][nt 8][L 64][j 8]                =  49152 halves (logits B, split-f16)
//   Kvec  : fp32[128] at byte offset 630784
#define WFRAG_OFF 0
#define W0FRAG_OFF 262144
#define BMAT_OFF   (262144 + 4096)
#define KVEC_BYTE_OFF 630784
#define WS_BYTES_NEEDED (630784 + 512)

__global__ __launch_bounds__(256) void prep_kernel(
    const float* __restrict__ centers, const float* __restrict__ sigmas,
    const float* __restrict__ W, _Float16* __restrict__ wsh, float* __restrict__ kvec)
{
    int t = blockIdx.x * 256 + threadIdx.x;
    if (t < 262144) {
        // Wfrag: B[k=i][n=o] fragments per rule r, k-step s
        int j = t & 7, L = (t >> 3) & 63, nt = (t >> 9) & 1, s = (t >> 10) & 1, r = t >> 11;
        int o = nt * 16 + (L & 15);
        int i = s * 32 + ((L >> 4) & 3) * 8 + j;
        wsh[t] = (_Float16)W[o * WCOLS + r * 64 + i];
    } else if (t < 262144 + 4096) {
        // W0frag: B[k=r][n=o]
        int u = t - 262144;
        int j = u & 7, L = (u >> 3) & 63, nt = (u >> 9) & 1, s = (u >> 10) & 3;
        int q = (L >> 4) & 3;
        int r = s * 32 + q * 8 + j;
        int o = nt * 16 + (L & 15);
        wsh[t] = (_Float16)W[o * WCOLS + 8192 + r];
    } else if (t < 262144 + 4096 + 49152) {
        // Bmat (logits): slot groups g = s>>1:
        //   g0:-Sh  g1:-Sl  g2:-Sh  g3:CS2h  g4:CS2l  g5:CS2h
        // paired with A groups [X2h, X2h, X2l, Xh, Xh, Xl]
        int u = t - (262144 + 4096);
        int j = u & 7, L = (u >> 3) & 63, nt = (u >> 9) & 7, s = u >> 12; // s 0..11
        int q = (L >> 4) & 3;
        int i = (s & 1) * 32 + q * 8 + j;
        int n = nt * 16 + (L & 15);
        float sg = sigmas[i * NRULES + n];
        float S = H_CONST / (sg * sg) + EPS_CONST;
        float c = centers[i * NRULES + n];
        float CS2 = 2.0f * c * S;
        int g = s >> 1;
        _Float16 v;
        if (g == 0 || g == 2) {
            v = -(_Float16)S;
        } else if (g == 1) {
            _Float16 sh = (_Float16)S;
            v = -(_Float16)(S - (float)sh);
        } else if (g == 3 || g == 5) {
            v = (_Float16)CS2;
        } else {
            _Float16 ch = (_Float16)CS2;
            v = (_Float16)(CS2 - (float)ch);
        }
        wsh[t] = v;
    } else if (t < 262144 + 4096 + 49152 + 128) {
        int r = t - (262144 + 4096 + 49152);
        float acc = 0.f;
        for (int i = 0; i < 64; ++i) {
            float sg = sigmas[i * NRULES + r];
            float S = H_CONST / (sg * sg) + EPS_CONST;
            float c = centers[i * NRULES + r];
            acc += c * c * S;
        }
        kvec[r] = acc;
    }
}

__global__ __launch_bounds__(256) void main_kernel(
    const float* __restrict__ X, const float* __restrict__ bias,
    const _Float16* __restrict__ wsh, const float* __restrict__ kvec,
    float* __restrict__ out, float* __restrict__ frs_out)
{
    // LDS: 32768 + 16384 + 16384 = 65536 bytes exactly
    __shared__ _Float16 sXh[64 * 64];   // f16(X)            [row][i] swizzled
    __shared__ _Float16 sXl[64 * 64];   // f16(X - Xh)
    __shared__ _Float16 sX2h[64 * 64];  // f16(X^2)
    __shared__ _Float16 sX2l[64 * 64];  // f16(X^2 - X2h)
    __shared__ _Float16 sFrs[64 * 128]; // frs f16, swizzled
    __shared__ float    sU[32 * 128];   // union: logits rounds (32 rows) / reduce [64][32]

    const int t = threadIdx.x;
    const int w = t >> 6;   // wave 0..3
    const int L = t & 63;   // lane
    const int m = L & 15;
    const int q = L >> 4;
    const int row0 = blockIdx.x * 64;

    // ---------------- Phase A: stage X splits into LDS ----------------
    // 512 units of 8 elements (row 0..63, unit-col 0..7), 2 per thread.
#pragma unroll
    for (int uu = 0; uu < 2; ++uu) {
        int u = t + uu * 256;
        int row = u >> 3, uc = u & 7;
        const float* gx = X + (row0 + row) * 64 + uc * 8;
        floatx4 xa = *(const floatx4*)gx;
        floatx4 xb = *(const floatx4*)(gx + 4);
        int base = row * 64 + (uc ^ (row & 7)) * 8;
        half8 vh, vl, v2h, v2l;
#pragma unroll
        for (int k = 0; k < 8; ++k) {
            float x = (k < 4) ? xa[k & 3] : xb[k & 3];
            _Float16 xh = (_Float16)x;
            _Float16 xl = (_Float16)(x - (float)xh);
            float x2 = x * x;
            _Float16 x2h = (_Float16)x2;
            _Float16 x2l = (_Float16)(x2 - (float)x2h);
            vh[k] = xh; vl[k] = xl; v2h[k] = x2h; v2l[k] = x2l;
        }
        *(half8*)(sXh + base) = vh;
        *(half8*)(sXl + base) = vl;
        *(half8*)(sX2h + base) = v2h;
        *(half8*)(sX2l + base) = v2l;
    }
    __syncthreads();

    // ---------------- Phase B: logits GEMM (split-f16) ----------------
    // wave w handles rule n-tiles {2w, 2w+1}; all 4 row m-tiles.
    floatx4 lacc[4][2];
#pragma unroll
    for (int mt = 0; mt < 4; ++mt)
#pragma unroll
        for (int n = 0; n < 2; ++n)
            lacc[mt][n] = (floatx4){0.f, 0.f, 0.f, 0.f};

    const _Float16* Bm = wsh + BMAT_OFF;
#pragma unroll
    for (int s = 0; s < 12; ++s) {
        const _Float16* arr = (s < 4) ? sX2h : (s < 6) ? sX2l : (s < 10) ? sXh : sXl;
        int iset = s & 1;
        int phys = ((iset << 2) | q) ^ (m & 7);
        half8 b0 = *(const half8*)(Bm + ((s * 8 + 2 * w + 0) * 64 + L) * 8);
        half8 b1 = *(const half8*)(Bm + ((s * 8 + 2 * w + 1) * 64 + L) * 8);
#pragma unroll
        for (int mt = 0; mt < 4; ++mt) {
            half8 a = *(const half8*)(arr + (mt * 16 + m) * 64 + phys * 8);
            lacc[mt][0] = MFMA16(a, b0, lacc[mt][0]);
            lacc[mt][1] = MFMA16(a, b1, lacc[mt][1]);
        }
    }
    float kv0 = kvec[(2 * w + 0) * 16 + m];
    float kv1 = kvec[(2 * w + 1) * 16 + m];

    // ---------------- Phase C: softmax (two 32-row rounds through sU) ----------------
#pragma unroll
    for (int h = 0; h < 2; ++h) {
#pragma unroll
        for (int mh = 0; mh < 2; ++mh) {
            int mt = 2 * h + mh;
#pragma unroll
            for (int ntl = 0; ntl < 2; ++ntl) {
                int col = (2 * w + ntl) * 16 + m;
                float kvv = ntl ? kv1 : kv0;
#pragma unroll
                for (int reg = 0; reg < 4; ++reg) {
                    int rl = mh * 16 + q * 4 + reg; // row in round, 0..31
                    sU[rl * 128 + (col ^ rl)] = lacc[mt][ntl][reg] - kvv;
                }
            }
        }
        __syncthreads();
        if (t < 32) {
            int rl = t;
            int grow = h * 32 + rl;
            float mx = -1e30f;
            for (int c = 0; c < 128; ++c) mx = fmaxf(mx, sU[rl * 128 + (c ^ rl)]);
            float sum = 0.f;
            for (int c = 0; c < 128; ++c) {
                float e = __expf(sU[rl * 128 + (c ^ rl)] - mx);
                sum += e;
                sU[rl * 128 + (c ^ rl)] = e;
            }
            float inv = 1.0f / sum;
            for (int c = 0; c < 128; ++c) {
                float f = sU[rl * 128 + (c ^ rl)] * inv;
                sFrs[grow * 128 + ((c >> 3) ^ (grow & 7)) * 8 + (c & 7)] = (_Float16)f;
            }
        }
        __syncthreads();
    }

    // frs fp32 write-out (from f16; err ~5e-4 << 2e-2 threshold), fully coalesced
#pragma unroll
    for (int uu = 0; uu < 4; ++uu) {
        int u = t + uu * 256;
        int row = u >> 4, uc = u & 15;
        half8 v = *(const half8*)(sFrs + row * 128 + (uc ^ (row & 7)) * 8);
        floatx4 f0, f1;
#pragma unroll
        for (int k = 0; k < 4; ++k) { f0[k] = (float)v[k]; f1[k] = (float)v[k + 4]; }
        float* gp = frs_out + (row0 + row) * 128 + uc * 8;
        *(floatx4*)gp = f0;
        *(floatx4*)(gp + 4) = f1;
    }

    // ---------------- Phase D: main GEMM, rules split across waves ----------------
    half8 xf[4][2];
#pragma unroll
    for (int mt = 0; mt < 4; ++mt)
#pragma unroll
        for (int s = 0; s < 2; ++s) {
            int phys = ((s << 2) | q) ^ (m & 7);
            xf[mt][s] = *(const half8*)(sXh + (mt * 16 + m) * 64 + phys * 8);
        }

    floatx4 oacc[4][2];
#pragma unroll
    for (int mt = 0; mt < 4; ++mt)
#pragma unroll
        for (int n = 0; n < 2; ++n)
            oacc[mt][n] = (floatx4){0.f, 0.f, 0.f, 0.f};

    const _Float16* Wf = wsh + WFRAG_OFF;
#pragma unroll 2
    for (int rr = 0; rr < 32; ++rr) {
        int r = w * 32 + rr;
        half8 b00 = *(const half8*)(Wf + (((r * 2 + 0) * 2 + 0) * 64 + L) * 8);
        half8 b01 = *(const half8*)(Wf + (((r * 2 + 0) * 2 + 1) * 64 + L) * 8);
        half8 b10 = *(const half8*)(Wf + (((r * 2 + 1) * 2 + 0) * 64 + L) * 8);
        half8 b11 = *(const half8*)(Wf + (((r * 2 + 1) * 2 + 1) * 64 + L) * 8);
#pragma unroll
        for (int mt = 0; mt < 4; ++mt) {
            int row = mt * 16 + m;
            _Float16 f = sFrs[row * 128 + ((r >> 3) ^ (row & 7)) * 8 + (r & 7)];
            half8 fs;
#pragma unroll
            for (int k = 0; k < 8; ++k) fs[k] = f;
            half8 a0 = fs * xf[mt][0];   // v_pk_mul_f16
            half8 a1 = fs * xf[mt][1];
            oacc[mt][0] = MFMA16(a0, b00, oacc[mt][0]);
            oacc[mt][0] = MFMA16(a1, b10, oacc[mt][0]);
            oacc[mt][1] = MFMA16(a0, b01, oacc[mt][1]);
            oacc[mt][1] = MFMA16(a1, b11, oacc[mt][1]);
        }
    }

    // ---------------- Phase E: W0 term (frs @ W0t), wave w covers m-tile w ----------------
    {
        const _Float16* W0f = wsh + W0FRAG_OFF;
        int row = w * 16 + m;
#pragma unroll
        for (int s = 0; s < 4; ++s) {
            int phys = ((s << 2) | q) ^ (row & 7); // frs unit index 0..15
            half8 a = *(const half8*)(sFrs + row * 128 + phys * 8);
            half8 b0 = *(const half8*)(W0f + ((s * 2 + 0) * 64 + L) * 8);
            half8 b1 = *(const half8*)(W0f + ((s * 2 + 1) * 64 + L) * 8);
#pragma unroll
            for (int mt = 0; mt < 4; ++mt) {
                if (mt == w) {
                    oacc[mt][0] = MFMA16(a, b0, oacc[mt][0]);
                    oacc[mt][1] = MFMA16(a, b1, oacc[mt][1]);
                }
            }
        }
    }

    // ---------------- Phase F: cross-wave reduce + bias + store ----------------
    float* sR = sU; // reuse as [64][32]
#pragma unroll
    for (int ww = 0; ww < 4; ++ww) {
        if (w == ww) {
#pragma unroll
            for (int mt = 0; mt < 4; ++mt)
#pragma unroll
                for (int ntl = 0; ntl < 2; ++ntl)
#pragma unroll
                    for (int reg = 0; reg < 4; ++reg) {
                        int row = mt * 16 + q * 4 + reg;
                        int col = ntl * 16 + m;
                        if (ww == 0) sR[row * 32 + col] = oacc[mt][ntl][reg];
                        else         sR[row * 32 + col] += oacc[mt][ntl][reg];
                    }
        }
        __syncthreads();
    }
#pragma unroll
    for (int k0 = 0; k0 < 8; ++k0) {
        int idx = t + k0 * 256;
        int row = idx >> 5, col = idx & 31;
        out[(row0 + row) * 32 + col] = sR[idx] + bias[col];
    }
}

extern "C" void kernel_launch(void* const* d_in, const int* in_sizes, int n_in,
                              void* d_out, int out_size, void* d_ws, size_t ws_size,
                              hipStream_t stream) {
    const float* X = (const float*)d_in[0];
    const float* centers = (const float*)d_in[1];
    const float* sigmas = (const float*)d_in[2];
    const float* W = (const float*)d_in[3];
    const float* b = (const float*)d_in[4];
    float* outp = (float*)d_out;               // [16384*32]
    float* frs_out = outp + NROWS * 32;        // [16384*128]
    if (ws_size < (size_t)WS_BYTES_NEEDED) return; // should never happen
    _Float16* wsh = (_Float16*)d_ws;
    float* kvec = (float*)((char*)d_ws + KVEC_BYTE_OFF);

    // total prep elements: 262144 + 4096 + 49152 + 128 = 315520
    prep_kernel<<<(315520 + 255) / 256, 256, 0, stream>>>(centers, sigmas, W, wsh, kvec);
    main_kernel<<<NROWS / 64, 256, 0, stream>>>(X, b, wsh, kvec, outp, frs_out);
}

// Round 2
// 97.641 us; speedup vs baseline: 1.0818x; 1.0818x over previous
//
#include <hip/hip_runtime.h>

// HTSK fuzzy-TSK fused pipeline for MI355X (gfx950), round 2.
// prep: build f16 MFMA B-fragments for W, W0, and split-f16 logits B-matrix + kvec.
// k1  : logits MFMA + parallel softmax -> frs fp32 (d_out) + bias-init of out.
// k2  : split-K GEMM out += [frs*X | frs] @ W.T via fp32 atomics (4 rule-groups).
// d_out = [out fp32 16384*32][frs fp32 16384*128]

#define H_CONST 0.5f
#define EPS_CONST 1e-8f
#define NROWS 16384
#define NRULES 128
#define WCOLS 8320

typedef _Float16 half8 __attribute__((ext_vector_type(8)));
typedef float floatx4 __attribute__((ext_vector_type(4)));

#define MFMA16(a, b, c) __builtin_amdgcn_mfma_f32_16x16x32_f16((a), (b), (c), 0, 0, 0)

// ws layout (halves) — identical to validated round-1 layout:
//   Wfrag : [r 128][s 2][nt 2][L 64][j 8]  = 262144 halves
//   W0frag: [s 4][nt 2][L 64][j 8]         =   4096 halves
//   Bmat  : [s 12][nt 8][L 64][j 8]        =  49152 halves
//   Kvec  : fp32[128] at byte offset 630784
#define WFRAG_OFF 0
#define W0FRAG_OFF 262144
#define BMAT_OFF   (262144 + 4096)
#define KVEC_BYTE_OFF 630784
#define WS_BYTES_NEEDED (630784 + 512)

// ---------------------------------------------------------------------------
// prep: 137 blocks x 256.  b<128: Wfrag rule b.  b in 128..135: Bmat nt=b-128.
//       b==136: W0frag + kvec.
// ---------------------------------------------------------------------------
__global__ __launch_bounds__(256) void prep_kernel(
    const float* __restrict__ centers, const float* __restrict__ sigmas,
    const float* __restrict__ W, _Float16* __restrict__ wsh, float* __restrict__ kvec)
{
    __shared__ float sBuf[32 * 68]; // 2176 floats; Bmat blocks reuse as sS(1088)+sC(1088)
    const int t = threadIdx.x;
    const int b = blockIdx.x;

    if (b < 128) {
        // ---- Wfrag for rule r = b ----
        const int r = b;
        {   // stage W[o][r*64 + i], o 0..31, i 0..63 -> sBuf[o*68 + i] (coalesced 256B/row)
            int o = t >> 3, seg = t & 7;
            const float* g = W + o * WCOLS + r * 64 + seg * 8;
            floatx4 a = *(const floatx4*)g;
            floatx4 c = *(const floatx4*)(g + 4);
            *(floatx4*)(sBuf + o * 68 + seg * 8) = a;
            *(floatx4*)(sBuf + o * 68 + seg * 8 + 4) = c;
        }
        __syncthreads();
        {   // write fragment order [s2][nt2][L64][j8]; thread t -> halves t*8..t*8+7
            int L = t & 63, nt = (t >> 6) & 1, s = t >> 7;
            int o = nt * 16 + (L & 15);
            int ib = s * 32 + ((L >> 4) & 3) * 8;
            floatx4 fa = *(const floatx4*)(sBuf + o * 68 + ib);
            floatx4 fb = *(const floatx4*)(sBuf + o * 68 + ib + 4);
            half8 h;
#pragma unroll
            for (int k = 0; k < 8; ++k) h[k] = (_Float16)((k < 4) ? fa[k & 3] : fb[k & 3]);
            *(half8*)(wsh + WFRAG_OFF + r * 2048 + t * 8) = h;
        }
    } else if (b < 136) {
        // ---- Bmat for nt = b - 128 ----
        const int nt = b - 128;
        float* sS = sBuf;          // [64][17]
        float* sC = sBuf + 1088;   // [64][17]
        {   // stage sigmas/centers cols nt*16..nt*16+15, rows 0..63 (float4 coalesced)
            int i = t >> 2, c0 = (t & 3) * 4;
            floatx4 sg4 = *(const floatx4*)(sigmas + i * NRULES + nt * 16 + c0);
            floatx4 ct4 = *(const floatx4*)(centers + i * NRULES + nt * 16 + c0);
#pragma unroll
            for (int k = 0; k < 4; ++k) { sS[i * 17 + c0 + k] = sg4[k]; sC[i * 17 + c0 + k] = ct4[k]; }
        }
        __syncthreads();
#pragma unroll
        for (int kk = 0; kk < 3; ++kk) {
            int unit = t + kk * 256;           // 768 units = 12 s x 64 L
            int s = unit >> 6, L = unit & 63;
            int q = (L >> 4) & 3, nl = L & 15;
            int g = s >> 1;
            int i0 = (s & 1) * 32 + q * 8;
            half8 h;
#pragma unroll
            for (int j = 0; j < 8; ++j) {
                int i = i0 + j;
                float sg = sS[i * 17 + nl];
                float S = H_CONST / (sg * sg) + EPS_CONST;
                float c = sC[i * 17 + nl];
                float CS2 = 2.0f * c * S;
                _Float16 v;
                if (g == 0 || g == 2) v = -(_Float16)S;
                else if (g == 1) { _Float16 sh = (_Float16)S; v = -(_Float16)(S - (float)sh); }
                else if (g == 3 || g == 5) v = (_Float16)CS2;
                else { _Float16 ch = (_Float16)CS2; v = (_Float16)(CS2 - (float)ch); }
                h[j] = v;
            }
            *(half8*)(wsh + BMAT_OFF + ((s * 8 + nt) * 64 + L) * 8) = h;
        }
    } else {
        // ---- W0frag + kvec ----
#pragma unroll
        for (int kk = 0; kk < 2; ++kk) {
            int unit = t + kk * 256;          // 512 units = 4 s x 2 nt x 64 L
            int s = unit >> 7, nt = (unit >> 6) & 1, L = unit & 63;
            int q = (L >> 4) & 3;
            int o = nt * 16 + (L & 15);
            half8 h;
#pragma unroll
            for (int j = 0; j < 8; ++j) {
                int r = s * 32 + q * 8 + j;
                h[j] = (_Float16)W[o * WCOLS + 8192 + r];
            }
            *(half8*)(wsh + W0FRAG_OFF + ((s * 2 + nt) * 64 + L) * 8) = h;
        }
        if (t < 128) {
            int r = t;
            float acc = 0.f;
#pragma unroll 8
            for (int i = 0; i < 64; ++i) {
                float sg = sigmas[i * NRULES + r];
                float S = H_CONST / (sg * sg) + EPS_CONST;
                float c = centers[i * NRULES + r];
                acc += c * c * S;
            }
            kvec[r] = acc;
        }
    }
}

// ---------------------------------------------------------------------------
// k1: 512 blocks x 256, 32 rows/block. logits (split-f16 MFMA) + parallel
//     softmax -> frs fp32 to d_out; also writes out := bias.
// ---------------------------------------------------------------------------
__global__ __launch_bounds__(256) void k1_frs(
    const float* __restrict__ X, const float* __restrict__ bias,
    const _Float16* __restrict__ wsh, const float* __restrict__ kvec,
    float* __restrict__ out, float* __restrict__ frs_out)
{
    __shared__ _Float16 sXh[32 * 64];
    __shared__ _Float16 sXl[32 * 64];
    __shared__ _Float16 sX2h[32 * 64];
    __shared__ _Float16 sX2l[32 * 64];
    __shared__ float sU[32 * 132];  // pad 132 to break bank aliasing

    const int t = threadIdx.x;
    const int w = t >> 6;
    const int L = t & 63;
    const int m = L & 15;
    const int q = L >> 4;
    const int row0 = blockIdx.x * 32;

    // stage X splits (1 unit of 8 per thread; round-1 swizzle)
    {
        int row = t >> 3, uc = t & 7;
        const float* gx = X + (row0 + row) * 64 + uc * 8;
        floatx4 xa = *(const floatx4*)gx;
        floatx4 xb = *(const floatx4*)(gx + 4);
        int base = row * 64 + (uc ^ (row & 7)) * 8;
        half8 vh, vl, v2h, v2l;
#pragma unroll
        for (int k = 0; k < 8; ++k) {
            float x = (k < 4) ? xa[k & 3] : xb[k & 3];
            _Float16 xh = (_Float16)x;
            _Float16 xl2 = (_Float16)(x - (float)xh);
            float x2 = x * x;
            _Float16 x2h = (_Float16)x2;
            _Float16 x2l = (_Float16)(x2 - (float)x2h);
            vh[k] = xh; vl[k] = xl2; v2h[k] = x2h; v2l[k] = x2l;
        }
        *(half8*)(sXh + base) = vh;
        *(half8*)(sXl + base) = vl;
        *(half8*)(sX2h + base) = v2h;
        *(half8*)(sX2l + base) = v2l;
    }
    __syncthreads();

    // logits MFMA: wave w -> rule n-tiles {2w, 2w+1}; m-tiles 0..1
    floatx4 lacc[2][2];
#pragma unroll
    for (int mt = 0; mt < 2; ++mt)
#pragma unroll
        for (int n = 0; n < 2; ++n) lacc[mt][n] = (floatx4){0.f, 0.f, 0.f, 0.f};

    const _Float16* Bm = wsh + BMAT_OFF;
#pragma unroll
    for (int s = 0; s < 12; ++s) {
        const _Float16* arr = (s < 4) ? sX2h : (s < 6) ? sX2l : (s < 10) ? sXh : sXl;
        int phys = (((s & 1) << 2) | q) ^ (m & 7);
        half8 b0 = *(const half8*)(Bm + ((s * 8 + 2 * w + 0) * 64 + L) * 8);
        half8 b1 = *(const half8*)(Bm + ((s * 8 + 2 * w + 1) * 64 + L) * 8);
#pragma unroll
        for (int mt = 0; mt < 2; ++mt) {
            half8 a = *(const half8*)(arr + (mt * 16 + m) * 64 + phys * 8);
            lacc[mt][0] = MFMA16(a, b0, lacc[mt][0]);
            lacc[mt][1] = MFMA16(a, b1, lacc[mt][1]);
        }
    }
    float kv0 = kvec[(2 * w + 0) * 16 + m];
    float kv1 = kvec[(2 * w + 1) * 16 + m];

#pragma unroll
    for (int mt = 0; mt < 2; ++mt)
#pragma unroll
        for (int ntl = 0; ntl < 2; ++ntl)
#pragma unroll
            for (int reg = 0; reg < 4; ++reg) {
                int rl = mt * 16 + q * 4 + reg;
                int col = (2 * w + ntl) * 16 + m;
                sU[rl * 132 + col] = lacc[mt][ntl][reg] - (ntl ? kv1 : kv0);
            }
    __syncthreads();

    // parallel softmax: 8 threads per row, 16 cols each, shuffle-reduce
    {
        int row = t >> 3, l8 = t & 7;
        int base = row * 132 + l8 * 16;
        float v[16];
        float mx = -1e30f;
#pragma unroll
        for (int k = 0; k < 16; ++k) { v[k] = sU[base + k]; mx = fmaxf(mx, v[k]); }
        mx = fmaxf(mx, __shfl_xor(mx, 1));
        mx = fmaxf(mx, __shfl_xor(mx, 2));
        mx = fmaxf(mx, __shfl_xor(mx, 4));
        float sum = 0.f;
#pragma unroll
        for (int k = 0; k < 16; ++k) { v[k] = __expf(v[k] - mx); sum += v[k]; }
        sum += __shfl_xor(sum, 1);
        sum += __shfl_xor(sum, 2);
        sum += __shfl_xor(sum, 4);
        float inv = 1.0f / sum;
        float* gf = frs_out + (row0 + row) * 128 + l8 * 16;
#pragma unroll
        for (int c = 0; c < 4; ++c) {
            floatx4 o4;
#pragma unroll
            for (int k = 0; k < 4; ++k) o4[k] = v[c * 4 + k] * inv;
            *(floatx4*)(gf + c * 4) = o4;
        }
    }

    // out := bias (so k2 can atomically accumulate partials)
    {
        int ro = t >> 3, c0 = (t & 7) * 4;
        floatx4 b4 = *(const floatx4*)(bias + c0);
        *(floatx4*)(out + (row0 + ro) * 32 + c0) = b4;
    }
}

// ---------------------------------------------------------------------------
// k2: 512 blocks x 256 = 128 row-blocks (128 rows) x 4 rule-groups (32 rules).
//     out += partial via fp32 atomics. W0 term folded per group.
// ---------------------------------------------------------------------------
__global__ __launch_bounds__(256) void k2_gemm(
    const float* __restrict__ X, const float* __restrict__ frs32,
    const _Float16* __restrict__ wsh, float* __restrict__ out)
{
    __shared__ _Float16 sXf[128 * 64];  // 16 KB, swizzled like round-1 sXh
    __shared__ _Float16 sF[128 * 40];   // 10 KB, row stride 40 halves (pad)

    const int t = threadIdx.x;
    const int w = t >> 6;
    const int L = t & 63;
    const int m = L & 15;
    const int q = L >> 4;
    const int rb = blockIdx.x >> 2;
    const int g = blockIdx.x & 3;
    const int row0 = rb * 128;

    // stage X (f16) and frs group (f16)
    {
        int row = t >> 1, hf = t & 1;
        const float* gx = X + (row0 + row) * 64 + hf * 32;
#pragma unroll
        for (int c = 0; c < 4; ++c) {
            int uc = hf * 4 + c;
            floatx4 a = *(const floatx4*)(gx + c * 8);
            floatx4 bb = *(const floatx4*)(gx + c * 8 + 4);
            half8 h;
#pragma unroll
            for (int k = 0; k < 8; ++k) h[k] = (_Float16)((k < 4) ? a[k & 3] : bb[k & 3]);
            *(half8*)(sXf + row * 64 + (uc ^ (row & 7)) * 8) = h;
        }
        const float* gfr = frs32 + (row0 + row) * 128 + g * 32 + hf * 16;
#pragma unroll
        for (int c = 0; c < 2; ++c) {
            floatx4 a = *(const floatx4*)(gfr + c * 8);
            floatx4 bb = *(const floatx4*)(gfr + c * 8 + 4);
            half8 h;
#pragma unroll
            for (int k = 0; k < 8; ++k) h[k] = (_Float16)((k < 4) ? a[k & 3] : bb[k & 3]);
            *(half8*)(sF + row * 40 + hf * 16 + c * 8) = h;
        }
    }
    __syncthreads();

    // per-wave A (X) fragments: wave w owns m-tiles {2w, 2w+1}
    half8 xf[2][2];
#pragma unroll
    for (int mtl = 0; mtl < 2; ++mtl) {
        int mt = 2 * w + mtl;
#pragma unroll
        for (int s = 0; s < 2; ++s) {
            int phys = ((s << 2) | q) ^ (m & 7);
            xf[mtl][s] = *(const half8*)(sXf + (mt * 16 + m) * 64 + phys * 8);
        }
    }

    floatx4 oacc[2][2];
#pragma unroll
    for (int mtl = 0; mtl < 2; ++mtl)
#pragma unroll
        for (int n = 0; n < 2; ++n) oacc[mtl][n] = (floatx4){0.f, 0.f, 0.f, 0.f};

    const _Float16* Wf = wsh + WFRAG_OFF;
    const _Float16* W0f = wsh + W0FRAG_OFF;

#pragma unroll 4
    for (int rr = 0; rr < 32; ++rr) {
        int r = g * 32 + rr;
        const _Float16* bp = Wf + r * 2048;
        half8 b00 = *(const half8*)(bp + (0 * 64 + L) * 8);
        half8 b01 = *(const half8*)(bp + (1 * 64 + L) * 8);
        half8 b10 = *(const half8*)(bp + (2 * 64 + L) * 8);
        half8 b11 = *(const half8*)(bp + (3 * 64 + L) * 8);
#pragma unroll
        for (int mtl = 0; mtl < 2; ++mtl) {
            int rowi = (2 * w + mtl) * 16 + m;
            _Float16 f = sF[rowi * 40 + rr];
            half8 fs;
#pragma unroll
            for (int k = 0; k < 8; ++k) fs[k] = f;
            half8 a0 = fs * xf[mtl][0];
            half8 a1 = fs * xf[mtl][1];
            oacc[mtl][0] = MFMA16(a0, b00, oacc[mtl][0]);
            oacc[mtl][0] = MFMA16(a1, b10, oacc[mtl][0]);
            oacc[mtl][1] = MFMA16(a0, b01, oacc[mtl][1]);
            oacc[mtl][1] = MFMA16(a1, b11, oacc[mtl][1]);
        }
    }

    // W0 term for this group's 32 rules (K=32 MFMA)
    {
        half8 b0 = *(const half8*)(W0f + ((g * 2 + 0) * 64 + L) * 8);
        half8 b1 = *(const half8*)(W0f + ((g * 2 + 1) * 64 + L) * 8);
#pragma unroll
        for (int mtl = 0; mtl < 2; ++mtl) {
            int rowi = (2 * w + mtl) * 16 + m;
            half8 a = *(const half8*)(sF + rowi * 40 + q * 8);
            oacc[mtl][0] = MFMA16(a, b0, oacc[mtl][0]);
            oacc[mtl][1] = MFMA16(a, b1, oacc[mtl][1]);
        }
    }

    // epilogue: atomic accumulate partials
#pragma unroll
    for (int mtl = 0; mtl < 2; ++mtl)
#pragma unroll
        for (int ntl = 0; ntl < 2; ++ntl)
#pragma unroll
            for (int reg = 0; reg < 4; ++reg) {
                int rowo = (2 * w + mtl) * 16 + q * 4 + reg;
                int colo = ntl * 16 + m;
                atomicAdd(out + (row0 + rowo) * 32 + colo, oacc[mtl][ntl][reg]);
            }
}

extern "C" void kernel_launch(void* const* d_in, const int* in_sizes, int n_in,
                              void* d_out, int out_size, void* d_ws, size_t ws_size,
                              hipStream_t stream) {
    const float* X = (const float*)d_in[0];
    const float* centers = (const float*)d_in[1];
    const float* sigmas = (const float*)d_in[2];
    const float* W = (const float*)d_in[3];
    const float* b = (const float*)d_in[4];
    float* outp = (float*)d_out;               // [16384*32]
    float* frs_out = outp + NROWS * 32;        // [16384*128]
    if (ws_size < (size_t)WS_BYTES_NEEDED) return;
    _Float16* wsh = (_Float16*)d_ws;
    float* kvec = (float*)((char*)d_ws + KVEC_BYTE_OFF);

    prep_kernel<<<137, 256, 0, stream>>>(centers, sigmas, W, wsh, kvec);
    k1_frs<<<NROWS / 32, 256, 0, stream>>>(X, b, wsh, kvec, outp, frs_out);
    k2_gemm<<<(NROWS / 128) * 4, 256, 0, stream>>>(X, frs_out, wsh, outp);
}

// Round 3
// 96.214 us; speedup vs baseline: 1.0979x; 1.0148x over previous
//
#include <hip/hip_runtime.h>

// HTSK fuzzy-TSK fused pipeline for MI355X (gfx950), round 3.
// prep: build f16 MFMA B-fragments for W, W0, split-f16 logits B-matrix + kvec.
// k1  : logits MFMA + parallel softmax -> frs fp32 (d_out).
// k2  : split-K GEMM partials[g] = (frs*X | frs)_g @ W_g.T  (plain stores, no atomics)
// k4  : out = sum_g partials[g] + bias.
// d_out = [out fp32 16384*32][frs fp32 16384*128]

#define H_CONST 0.5f
#define EPS_CONST 1e-8f
#define NROWS 16384
#define NRULES 128
#define WCOLS 8320

typedef _Float16 half8 __attribute__((ext_vector_type(8)));
typedef float floatx4 __attribute__((ext_vector_type(4)));

#define MFMA16(a, b, c) __builtin_amdgcn_mfma_f32_16x16x32_f16((a), (b), (c), 0, 0, 0)

// ws layout:
//   halves:
//   Wfrag : [r 128][s 2][nt 2][L 64][j 8]  = 262144 halves
//   W0frag: [s 4][nt 2][L 64][j 8]         =   4096 halves
//   Bmat  : [s 12][nt 8][L 64][j 8]        =  49152 halves
//   Kvec  : fp32[128]       at byte offset 630784
//   Part  : fp32[4][16384*32] at byte offset 1048576 (4 x 2MB split-K partials)
#define WFRAG_OFF 0
#define W0FRAG_OFF 262144
#define BMAT_OFF   (262144 + 4096)
#define KVEC_BYTE_OFF 630784
#define PART_BYTE_OFF 1048576
#define PART_STRIDE (NROWS * 32)
#define WS_BYTES_NEEDED (PART_BYTE_OFF + 4 * PART_STRIDE * 4)

// ---------------------------------------------------------------------------
// prep: 137 blocks x 256.  b<128: Wfrag rule b.  b in 128..135: Bmat nt=b-128.
//       b==136: W0frag + kvec.
// ---------------------------------------------------------------------------
__global__ __launch_bounds__(256) void prep_kernel(
    const float* __restrict__ centers, const float* __restrict__ sigmas,
    const float* __restrict__ W, _Float16* __restrict__ wsh, float* __restrict__ kvec)
{
    __shared__ float sBuf[32 * 68];
    const int t = threadIdx.x;
    const int b = blockIdx.x;

    if (b < 128) {
        const int r = b;
        {
            int o = t >> 3, seg = t & 7;
            const float* g = W + o * WCOLS + r * 64 + seg * 8;
            floatx4 a = *(const floatx4*)g;
            floatx4 c = *(const floatx4*)(g + 4);
            *(floatx4*)(sBuf + o * 68 + seg * 8) = a;
            *(floatx4*)(sBuf + o * 68 + seg * 8 + 4) = c;
        }
        __syncthreads();
        {
            int L = t & 63, nt = (t >> 6) & 1, s = t >> 7;
            int o = nt * 16 + (L & 15);
            int ib = s * 32 + ((L >> 4) & 3) * 8;
            floatx4 fa = *(const floatx4*)(sBuf + o * 68 + ib);
            floatx4 fb = *(const floatx4*)(sBuf + o * 68 + ib + 4);
            half8 h;
#pragma unroll
            for (int k = 0; k < 8; ++k) h[k] = (_Float16)((k < 4) ? fa[k & 3] : fb[k & 3]);
            *(half8*)(wsh + WFRAG_OFF + r * 2048 + t * 8) = h;
        }
    } else if (b < 136) {
        const int nt = b - 128;
        float* sS = sBuf;
        float* sC = sBuf + 1088;
        {
            int i = t >> 2, c0 = (t & 3) * 4;
            floatx4 sg4 = *(const floatx4*)(sigmas + i * NRULES + nt * 16 + c0);
            floatx4 ct4 = *(const floatx4*)(centers + i * NRULES + nt * 16 + c0);
#pragma unroll
            for (int k = 0; k < 4; ++k) { sS[i * 17 + c0 + k] = sg4[k]; sC[i * 17 + c0 + k] = ct4[k]; }
        }
        __syncthreads();
#pragma unroll
        for (int kk = 0; kk < 3; ++kk) {
            int unit = t + kk * 256;
            int s = unit >> 6, L = unit & 63;
            int q = (L >> 4) & 3, nl = L & 15;
            int g = s >> 1;
            int i0 = (s & 1) * 32 + q * 8;
            half8 h;
#pragma unroll
            for (int j = 0; j < 8; ++j) {
                int i = i0 + j;
                float sg = sS[i * 17 + nl];
                float S = H_CONST / (sg * sg) + EPS_CONST;
                float c = sC[i * 17 + nl];
                float CS2 = 2.0f * c * S;
                _Float16 v;
                if (g == 0 || g == 2) v = -(_Float16)S;
                else if (g == 1) { _Float16 sh = (_Float16)S; v = -(_Float16)(S - (float)sh); }
                else if (g == 3 || g == 5) v = (_Float16)CS2;
                else { _Float16 ch = (_Float16)CS2; v = (_Float16)(CS2 - (float)ch); }
                h[j] = v;
            }
            *(half8*)(wsh + BMAT_OFF + ((s * 8 + nt) * 64 + L) * 8) = h;
        }
    } else {
#pragma unroll
        for (int kk = 0; kk < 2; ++kk) {
            int unit = t + kk * 256;
            int s = unit >> 7, nt = (unit >> 6) & 1, L = unit & 63;
            int q = (L >> 4) & 3;
            int o = nt * 16 + (L & 15);
            half8 h;
#pragma unroll
            for (int j = 0; j < 8; ++j) {
                int r = s * 32 + q * 8 + j;
                h[j] = (_Float16)W[o * WCOLS + 8192 + r];
            }
            *(half8*)(wsh + W0FRAG_OFF + ((s * 2 + nt) * 64 + L) * 8) = h;
        }
        if (t < 128) {
            int r = t;
            float acc = 0.f;
#pragma unroll 8
            for (int i = 0; i < 64; ++i) {
                float sg = sigmas[i * NRULES + r];
                float S = H_CONST / (sg * sg) + EPS_CONST;
                float c = centers[i * NRULES + r];
                acc += c * c * S;
            }
            kvec[r] = acc;
        }
    }
}

// ---------------------------------------------------------------------------
// k1: 512 blocks x 256, 32 rows/block. logits (split-f16 MFMA) + parallel
//     softmax -> frs fp32 to d_out.
// ---------------------------------------------------------------------------
__global__ __launch_bounds__(256) void k1_frs(
    const float* __restrict__ X,
    const _Float16* __restrict__ wsh, const float* __restrict__ kvec,
    float* __restrict__ frs_out)
{
    __shared__ _Float16 sXh[32 * 64];
    __shared__ _Float16 sXl[32 * 64];
    __shared__ _Float16 sX2h[32 * 64];
    __shared__ _Float16 sX2l[32 * 64];
    __shared__ float sU[32 * 132];

    const int t = threadIdx.x;
    const int w = t >> 6;
    const int L = t & 63;
    const int m = L & 15;
    const int q = L >> 4;
    const int row0 = blockIdx.x * 32;

    {
        int row = t >> 3, uc = t & 7;
        const float* gx = X + (row0 + row) * 64 + uc * 8;
        floatx4 xa = *(const floatx4*)gx;
        floatx4 xb = *(const floatx4*)(gx + 4);
        int base = row * 64 + (uc ^ (row & 7)) * 8;
        half8 vh, vl, v2h, v2l;
#pragma unroll
        for (int k = 0; k < 8; ++k) {
            float x = (k < 4) ? xa[k & 3] : xb[k & 3];
            _Float16 xh = (_Float16)x;
            _Float16 xl2 = (_Float16)(x - (float)xh);
            float x2 = x * x;
            _Float16 x2h = (_Float16)x2;
            _Float16 x2l = (_Float16)(x2 - (float)x2h);
            vh[k] = xh; vl[k] = xl2; v2h[k] = x2h; v2l[k] = x2l;
        }
        *(half8*)(sXh + base) = vh;
        *(half8*)(sXl + base) = vl;
        *(half8*)(sX2h + base) = v2h;
        *(half8*)(sX2l + base) = v2l;
    }
    __syncthreads();

    floatx4 lacc[2][2];
#pragma unroll
    for (int mt = 0; mt < 2; ++mt)
#pragma unroll
        for (int n = 0; n < 2; ++n) lacc[mt][n] = (floatx4){0.f, 0.f, 0.f, 0.f};

    const _Float16* Bm = wsh + BMAT_OFF;
#pragma unroll
    for (int s = 0; s < 12; ++s) {
        const _Float16* arr = (s < 4) ? sX2h : (s < 6) ? sX2l : (s < 10) ? sXh : sXl;
        int phys = (((s & 1) << 2) | q) ^ (m & 7);
        half8 b0 = *(const half8*)(Bm + ((s * 8 + 2 * w + 0) * 64 + L) * 8);
        half8 b1 = *(const half8*)(Bm + ((s * 8 + 2 * w + 1) * 64 + L) * 8);
#pragma unroll
        for (int mt = 0; mt < 2; ++mt) {
            half8 a = *(const half8*)(arr + (mt * 16 + m) * 64 + phys * 8);
            lacc[mt][0] = MFMA16(a, b0, lacc[mt][0]);
            lacc[mt][1] = MFMA16(a, b1, lacc[mt][1]);
        }
    }
    float kv0 = kvec[(2 * w + 0) * 16 + m];
    float kv1 = kvec[(2 * w + 1) * 16 + m];

#pragma unroll
    for (int mt = 0; mt < 2; ++mt)
#pragma unroll
        for (int ntl = 0; ntl < 2; ++ntl)
#pragma unroll
            for (int reg = 0; reg < 4; ++reg) {
                int rl = mt * 16 + q * 4 + reg;
                int col = (2 * w + ntl) * 16 + m;
                sU[rl * 132 + col] = lacc[mt][ntl][reg] - (ntl ? kv1 : kv0);
            }
    __syncthreads();

    {
        int row = t >> 3, l8 = t & 7;
        int base = row * 132 + l8 * 16;
        float v[16];
        float mx = -1e30f;
#pragma unroll
        for (int k = 0; k < 16; ++k) { v[k] = sU[base + k]; mx = fmaxf(mx, v[k]); }
        mx = fmaxf(mx, __shfl_xor(mx, 1));
        mx = fmaxf(mx, __shfl_xor(mx, 2));
        mx = fmaxf(mx, __shfl_xor(mx, 4));
        float sum = 0.f;
#pragma unroll
        for (int k = 0; k < 16; ++k) { v[k] = __expf(v[k] - mx); sum += v[k]; }
        sum += __shfl_xor(sum, 1);
        sum += __shfl_xor(sum, 2);
        sum += __shfl_xor(sum, 4);
        float inv = 1.0f / sum;
        float* gf = frs_out + (row0 + row) * 128 + l8 * 16;
#pragma unroll
        for (int c = 0; c < 4; ++c) {
            floatx4 o4;
#pragma unroll
            for (int k = 0; k < 4; ++k) o4[k] = v[c * 4 + k] * inv;
            *(floatx4*)(gf + c * 4) = o4;
        }
    }
}

// ---------------------------------------------------------------------------
// k2: 512 blocks x 256 = 128 row-blocks (128 rows) x 4 rule-groups (32 rules).
//     partials[g] written with plain coalesced stores (no atomics).
// ---------------------------------------------------------------------------
__global__ __launch_bounds__(256) void k2_gemm(
    const float* __restrict__ X, const float* __restrict__ frs32,
    const _Float16* __restrict__ wsh, float* __restrict__ part)
{
    __shared__ _Float16 sXf[128 * 64];
    __shared__ _Float16 sF[128 * 40];

    const int t = threadIdx.x;
    const int w = t >> 6;
    const int L = t & 63;
    const int m = L & 15;
    const int q = L >> 4;
    const int rb = blockIdx.x >> 2;
    const int g = blockIdx.x & 3;
    const int row0 = rb * 128;

    {
        int row = t >> 1, hf = t & 1;
        const float* gx = X + (row0 + row) * 64 + hf * 32;
#pragma unroll
        for (int c = 0; c < 4; ++c) {
            int uc = hf * 4 + c;
            floatx4 a = *(const floatx4*)(gx + c * 8);
            floatx4 bb = *(const floatx4*)(gx + c * 8 + 4);
            half8 h;
#pragma unroll
            for (int k = 0; k < 8; ++k) h[k] = (_Float16)((k < 4) ? a[k & 3] : bb[k & 3]);
            *(half8*)(sXf + row * 64 + (uc ^ (row & 7)) * 8) = h;
        }
        const float* gfr = frs32 + (row0 + row) * 128 + g * 32 + hf * 16;
#pragma unroll
        for (int c = 0; c < 2; ++c) {
            floatx4 a = *(const floatx4*)(gfr + c * 8);
            floatx4 bb = *(const floatx4*)(gfr + c * 8 + 4);
            half8 h;
#pragma unroll
            for (int k = 0; k < 8; ++k) h[k] = (_Float16)((k < 4) ? a[k & 3] : bb[k & 3]);
            *(half8*)(sF + row * 40 + hf * 16 + c * 8) = h;
        }
    }
    __syncthreads();

    half8 xf[2][2];
#pragma unroll
    for (int mtl = 0; mtl < 2; ++mtl) {
        int mt = 2 * w + mtl;
#pragma unroll
        for (int s = 0; s < 2; ++s) {
            int phys = ((s << 2) | q) ^ (m & 7);
            xf[mtl][s] = *(const half8*)(sXf + (mt * 16 + m) * 64 + phys * 8);
        }
    }

    floatx4 oacc[2][2];
#pragma unroll
    for (int mtl = 0; mtl < 2; ++mtl)
#pragma unroll
        for (int n = 0; n < 2; ++n) oacc[mtl][n] = (floatx4){0.f, 0.f, 0.f, 0.f};

    const _Float16* Wf = wsh + WFRAG_OFF;
    const _Float16* W0f = wsh + W0FRAG_OFF;

#pragma unroll 4
    for (int rr = 0; rr < 32; ++rr) {
        int r = g * 32 + rr;
        const _Float16* bp = Wf + r * 2048;
        half8 b00 = *(const half8*)(bp + (0 * 64 + L) * 8);
        half8 b01 = *(const half8*)(bp + (1 * 64 + L) * 8);
        half8 b10 = *(const half8*)(bp + (2 * 64 + L) * 8);
        half8 b11 = *(const half8*)(bp + (3 * 64 + L) * 8);
#pragma unroll
        for (int mtl = 0; mtl < 2; ++mtl) {
            int rowi = (2 * w + mtl) * 16 + m;
            _Float16 f = sF[rowi * 40 + rr];
            half8 fs;
#pragma unroll
            for (int k = 0; k < 8; ++k) fs[k] = f;
            half8 a0 = fs * xf[mtl][0];
            half8 a1 = fs * xf[mtl][1];
            oacc[mtl][0] = MFMA16(a0, b00, oacc[mtl][0]);
            oacc[mtl][0] = MFMA16(a1, b10, oacc[mtl][0]);
            oacc[mtl][1] = MFMA16(a0, b01, oacc[mtl][1]);
            oacc[mtl][1] = MFMA16(a1, b11, oacc[mtl][1]);
        }
    }

    {
        half8 b0 = *(const half8*)(W0f + ((g * 2 + 0) * 64 + L) * 8);
        half8 b1 = *(const half8*)(W0f + ((g * 2 + 1) * 64 + L) * 8);
#pragma unroll
        for (int mtl = 0; mtl < 2; ++mtl) {
            int rowi = (2 * w + mtl) * 16 + m;
            half8 a = *(const half8*)(sF + rowi * 40 + q * 8);
            oacc[mtl][0] = MFMA16(a, b0, oacc[mtl][0]);
            oacc[mtl][1] = MFMA16(a, b1, oacc[mtl][1]);
        }
    }

    // epilogue: plain stores of this group's partial
    float* pg = part + g * PART_STRIDE;
#pragma unroll
    for (int mtl = 0; mtl < 2; ++mtl)
#pragma unroll
        for (int ntl = 0; ntl < 2; ++ntl)
#pragma unroll
            for (int reg = 0; reg < 4; ++reg) {
                int rowo = (2 * w + mtl) * 16 + q * 4 + reg;
                int colo = ntl * 16 + m;
                pg[(row0 + rowo) * 32 + colo] = oacc[mtl][ntl][reg];
            }
}

// ---------------------------------------------------------------------------
// k4: out = sum_g part[g] + bias.  512 blocks x 256, one float4 per thread.
// ---------------------------------------------------------------------------
__global__ __launch_bounds__(256) void k4_reduce(
    const float* __restrict__ part, const float* __restrict__ bias,
    float* __restrict__ out)
{
    int gt = blockIdx.x * 256 + threadIdx.x;   // 131072 threads
    int idx = gt * 4;                           // flat float index into [16384*32]
    floatx4 a0 = *(const floatx4*)(part + 0 * PART_STRIDE + idx);
    floatx4 a1 = *(const floatx4*)(part + 1 * PART_STRIDE + idx);
    floatx4 a2 = *(const floatx4*)(part + 2 * PART_STRIDE + idx);
    floatx4 a3 = *(const floatx4*)(part + 3 * PART_STRIDE + idx);
    floatx4 b4 = *(const floatx4*)(bias + (idx & 31));
    floatx4 r = (a0 + a1) + (a2 + a3) + b4;
    *(floatx4*)(out + idx) = r;
}

extern "C" void kernel_launch(void* const* d_in, const int* in_sizes, int n_in,
                              void* d_out, int out_size, void* d_ws, size_t ws_size,
                              hipStream_t stream) {
    const float* X = (const float*)d_in[0];
    const float* centers = (const float*)d_in[1];
    const float* sigmas = (const float*)d_in[2];
    const float* W = (const float*)d_in[3];
    const float* b = (const float*)d_in[4];
    float* outp = (float*)d_out;               // [16384*32]
    float* frs_out = outp + NROWS * 32;        // [16384*128]
    if (ws_size < (size_t)WS_BYTES_NEEDED) return;
    _Float16* wsh = (_Float16*)d_ws;
    float* kvec = (float*)((char*)d_ws + KVEC_BYTE_OFF);
    float* part = (float*)((char*)d_ws + PART_BYTE_OFF);

    prep_kernel<<<137, 256, 0, stream>>>(centers, sigmas, W, wsh, kvec);
    k1_frs<<<NROWS / 32, 256, 0, stream>>>(X, wsh, kvec, frs_out);
    k2_gemm<<<(NROWS / 128) * 4, 256, 0, stream>>>(X, frs_out, wsh, part);
    k4_reduce<<<512, 256, 0, stream>>>(part, b, outp);
}

// Round 4
// 92.848 us; speedup vs baseline: 1.1377x; 1.0363x over previous
//
#include <hip/hip_runtime.h>

// HTSK fuzzy-TSK fused pipeline for MI355X (gfx950), round 4.
// prep: build f16 MFMA B-fragments for W, W0, split-f16 logits B-matrix + kvec.
// main: (fused) logits MFMA -> softmax -> frs out + GEMM out, one block = 32 rows.
// d_out = [out fp32 16384*32][frs fp32 16384*128]

#define H_CONST 0.5f
#define EPS_CONST 1e-8f
#define NROWS 16384
#define NRULES 128
#define WCOLS 8320

typedef _Float16 half8 __attribute__((ext_vector_type(8)));
typedef float floatx4 __attribute__((ext_vector_type(4)));

#define MFMA16(a, b, c) __builtin_amdgcn_mfma_f32_16x16x32_f16((a), (b), (c), 0, 0, 0)

// ws layout (halves):
//   Wfrag : [r 128][s 2][nt 2][L 64][j 8]  = 262144 halves
//   W0frag: [s 4][nt 2][L 64][j 8]         =   4096 halves
//   Bmat  : [s 12][nt 8][L 64][j 8]        =  49152 halves
//   Kvec  : fp32[128] at byte offset 630784
#define WFRAG_OFF 0
#define W0FRAG_OFF 262144
#define BMAT_OFF   (262144 + 4096)
#define KVEC_BYTE_OFF 630784
#define WS_BYTES_NEEDED (630784 + 512)

// ---------------------------------------------------------------------------
// prep: 137 blocks x 256.  b<128: Wfrag rule b.  b in 128..135: Bmat nt=b-128.
//       b==136: W0frag + kvec.   (validated in rounds 2-3)
// ---------------------------------------------------------------------------
__global__ __launch_bounds__(256) void prep_kernel(
    const float* __restrict__ centers, const float* __restrict__ sigmas,
    const float* __restrict__ W, _Float16* __restrict__ wsh, float* __restrict__ kvec)
{
    __shared__ float sBuf[32 * 68];
    const int t = threadIdx.x;
    const int b = blockIdx.x;

    if (b < 128) {
        const int r = b;
        {
            int o = t >> 3, seg = t & 7;
            const float* g = W + o * WCOLS + r * 64 + seg * 8;
            floatx4 a = *(const floatx4*)g;
            floatx4 c = *(const floatx4*)(g + 4);
            *(floatx4*)(sBuf + o * 68 + seg * 8) = a;
            *(floatx4*)(sBuf + o * 68 + seg * 8 + 4) = c;
        }
        __syncthreads();
        {
            int L = t & 63, nt = (t >> 6) & 1, s = t >> 7;
            int o = nt * 16 + (L & 15);
            int ib = s * 32 + ((L >> 4) & 3) * 8;
            floatx4 fa = *(const floatx4*)(sBuf + o * 68 + ib);
            floatx4 fb = *(const floatx4*)(sBuf + o * 68 + ib + 4);
            half8 h;
#pragma unroll
            for (int k = 0; k < 8; ++k) h[k] = (_Float16)((k < 4) ? fa[k & 3] : fb[k & 3]);
            *(half8*)(wsh + WFRAG_OFF + r * 2048 + t * 8) = h;
        }
    } else if (b < 136) {
        const int nt = b - 128;
        float* sS = sBuf;
        float* sC = sBuf + 1088;
        {
            int i = t >> 2, c0 = (t & 3) * 4;
            floatx4 sg4 = *(const floatx4*)(sigmas + i * NRULES + nt * 16 + c0);
            floatx4 ct4 = *(const floatx4*)(centers + i * NRULES + nt * 16 + c0);
#pragma unroll
            for (int k = 0; k < 4; ++k) { sS[i * 17 + c0 + k] = sg4[k]; sC[i * 17 + c0 + k] = ct4[k]; }
        }
        __syncthreads();
#pragma unroll
        for (int kk = 0; kk < 3; ++kk) {
            int unit = t + kk * 256;
            int s = unit >> 6, L = unit & 63;
            int q = (L >> 4) & 3, nl = L & 15;
            int g = s >> 1;
            int i0 = (s & 1) * 32 + q * 8;
            half8 h;
#pragma unroll
            for (int j = 0; j < 8; ++j) {
                int i = i0 + j;
                float sg = sS[i * 17 + nl];
                float S = H_CONST / (sg * sg) + EPS_CONST;
                float c = sC[i * 17 + nl];
                float CS2 = 2.0f * c * S;
                _Float16 v;
                if (g == 0 || g == 2) v = -(_Float16)S;
                else if (g == 1) { _Float16 sh = (_Float16)S; v = -(_Float16)(S - (float)sh); }
                else if (g == 3 || g == 5) v = (_Float16)CS2;
                else { _Float16 ch = (_Float16)CS2; v = (_Float16)(CS2 - (float)ch); }
                h[j] = v;
            }
            *(half8*)(wsh + BMAT_OFF + ((s * 8 + nt) * 64 + L) * 8) = h;
        }
    } else {
#pragma unroll
        for (int kk = 0; kk < 2; ++kk) {
            int unit = t + kk * 256;
            int s = unit >> 7, nt = (unit >> 6) & 1, L = unit & 63;
            int q = (L >> 4) & 3;
            int o = nt * 16 + (L & 15);
            half8 h;
#pragma unroll
            for (int j = 0; j < 8; ++j) {
                int r = s * 32 + q * 8 + j;
                h[j] = (_Float16)W[o * WCOLS + 8192 + r];
            }
            *(half8*)(wsh + W0FRAG_OFF + ((s * 2 + nt) * 64 + L) * 8) = h;
        }
        if (t < 128) {
            int r = t;
            float acc = 0.f;
#pragma unroll 8
            for (int i = 0; i < 64; ++i) {
                float sg = sigmas[i * NRULES + r];
                float S = H_CONST / (sg * sg) + EPS_CONST;
                float c = centers[i * NRULES + r];
                acc += c * c * S;
            }
            kvec[r] = acc;
        }
    }
}

// ---------------------------------------------------------------------------
// main (fused): 512 blocks x 256, 32 rows/block.
//   A: stage X splits -> LDS
//   B: logits MFMA (split-f16)
//   C: softmax -> frs fp32 global + frs f16 LDS
//   D: GEMM, wave w = (m-tile w&1, rule-half w>>1), 64 rules each, W0 folded
//   E: cross-half LDS reduce + bias + store out
// ---------------------------------------------------------------------------
__global__ __launch_bounds__(256) void main_fused(
    const float* __restrict__ X, const float* __restrict__ bias,
    const _Float16* __restrict__ wsh, const float* __restrict__ kvec,
    float* __restrict__ out, float* __restrict__ frs_out)
{
    __shared__ _Float16 sXh[32 * 64];
    __shared__ _Float16 sXl[32 * 64];
    __shared__ _Float16 sX2h[32 * 64];
    __shared__ _Float16 sX2l[32 * 64];
    __shared__ float sU[32 * 132];      // logits staging; aliased as sR (stride 33) in E
    __shared__ _Float16 sF[32 * 136];   // frs f16, row stride 136

    const int t = threadIdx.x;
    const int w = t >> 6;
    const int L = t & 63;
    const int m = L & 15;
    const int q = L >> 4;
    const int row0 = blockIdx.x * 32;

    // ---- A: stage X splits ----
    {
        int row = t >> 3, uc = t & 7;
        const float* gx = X + (row0 + row) * 64 + uc * 8;
        floatx4 xa = *(const floatx4*)gx;
        floatx4 xb = *(const floatx4*)(gx + 4);
        int base = row * 64 + (uc ^ (row & 7)) * 8;
        half8 vh, vl, v2h, v2l;
#pragma unroll
        for (int k = 0; k < 8; ++k) {
            float x = (k < 4) ? xa[k & 3] : xb[k & 3];
            _Float16 xh = (_Float16)x;
            _Float16 xl2 = (_Float16)(x - (float)xh);
            float x2 = x * x;
            _Float16 x2h = (_Float16)x2;
            _Float16 x2l = (_Float16)(x2 - (float)x2h);
            vh[k] = xh; vl[k] = xl2; v2h[k] = x2h; v2l[k] = x2l;
        }
        *(half8*)(sXh + base) = vh;
        *(half8*)(sXl + base) = vl;
        *(half8*)(sX2h + base) = v2h;
        *(half8*)(sX2l + base) = v2l;
    }
    __syncthreads();

    // ---- B: logits MFMA; wave w -> rule n-tiles {2w,2w+1}, m-tiles 0..1 ----
    floatx4 lacc[2][2];
#pragma unroll
    for (int mt = 0; mt < 2; ++mt)
#pragma unroll
        for (int n = 0; n < 2; ++n) lacc[mt][n] = (floatx4){0.f, 0.f, 0.f, 0.f};

    const _Float16* Bm = wsh + BMAT_OFF;
#pragma unroll
    for (int s = 0; s < 12; ++s) {
        const _Float16* arr = (s < 4) ? sX2h : (s < 6) ? sX2l : (s < 10) ? sXh : sXl;
        int phys = (((s & 1) << 2) | q) ^ (m & 7);
        half8 b0 = *(const half8*)(Bm + ((s * 8 + 2 * w + 0) * 64 + L) * 8);
        half8 b1 = *(const half8*)(Bm + ((s * 8 + 2 * w + 1) * 64 + L) * 8);
#pragma unroll
        for (int mt = 0; mt < 2; ++mt) {
            half8 a = *(const half8*)(arr + (mt * 16 + m) * 64 + phys * 8);
            lacc[mt][0] = MFMA16(a, b0, lacc[mt][0]);
            lacc[mt][1] = MFMA16(a, b1, lacc[mt][1]);
        }
    }
    float kv0 = kvec[(2 * w + 0) * 16 + m];
    float kv1 = kvec[(2 * w + 1) * 16 + m];

#pragma unroll
    for (int mt = 0; mt < 2; ++mt)
#pragma unroll
        for (int ntl = 0; ntl < 2; ++ntl)
#pragma unroll
            for (int reg = 0; reg < 4; ++reg) {
                int rl = mt * 16 + q * 4 + reg;
                int col = (2 * w + ntl) * 16 + m;
                sU[rl * 132 + col] = lacc[mt][ntl][reg] - (ntl ? kv1 : kv0);
            }
    __syncthreads();

    // ---- C: parallel softmax (8 threads/row); frs -> global fp32 + LDS f16 ----
    {
        int row = t >> 3, l8 = t & 7;
        int base = row * 132 + l8 * 16;
        float v[16];
        float mx = -1e30f;
#pragma unroll
        for (int k = 0; k < 16; ++k) { v[k] = sU[base + k]; mx = fmaxf(mx, v[k]); }
        mx = fmaxf(mx, __shfl_xor(mx, 1));
        mx = fmaxf(mx, __shfl_xor(mx, 2));
        mx = fmaxf(mx, __shfl_xor(mx, 4));
        float sum = 0.f;
#pragma unroll
        for (int k = 0; k < 16; ++k) { v[k] = __expf(v[k] - mx); sum += v[k]; }
        sum += __shfl_xor(sum, 1);
        sum += __shfl_xor(sum, 2);
        sum += __shfl_xor(sum, 4);
        float inv = 1.0f / sum;
        float* gf = frs_out + (row0 + row) * 128 + l8 * 16;
        half8 h0, h1;
#pragma unroll
        for (int c = 0; c < 4; ++c) {
            floatx4 o4;
#pragma unroll
            for (int k = 0; k < 4; ++k) {
                float f = v[c * 4 + k] * inv;
                o4[k] = f;
                if (c < 2) h0[c * 4 + k] = (_Float16)f; else h1[(c - 2) * 4 + k] = (_Float16)f;
            }
            *(floatx4*)(gf + c * 4) = o4;
        }
        *(half8*)(sF + row * 136 + l8 * 16) = h0;
        *(half8*)(sF + row * 136 + l8 * 16 + 8) = h1;
    }
    __syncthreads();   // sF ready; sU reads done (safe to alias later)

    // ---- D: main GEMM. wave w: mt = w&1, rule-half rh = w>>1 ----
    const int mt = w & 1;
    const int rh = w >> 1;

    half8 xf[2];
#pragma unroll
    for (int s = 0; s < 2; ++s) {
        int phys = ((s << 2) | q) ^ (m & 7);
        xf[s] = *(const half8*)(sXh + (mt * 16 + m) * 64 + phys * 8);
    }

    floatx4 oacc[2];
    oacc[0] = (floatx4){0.f, 0.f, 0.f, 0.f};
    oacc[1] = (floatx4){0.f, 0.f, 0.f, 0.f};

    const _Float16* Wf = wsh + WFRAG_OFF;
    const _Float16* W0f = wsh + W0FRAG_OFF;
    const int rowi = mt * 16 + m;

#pragma unroll 4
    for (int rr = 0; rr < 64; ++rr) {
        int r = rh * 64 + rr;
        const _Float16* bp = Wf + r * 2048;
        half8 b00 = *(const half8*)(bp + (0 * 64 + L) * 8);
        half8 b01 = *(const half8*)(bp + (1 * 64 + L) * 8);
        half8 b10 = *(const half8*)(bp + (2 * 64 + L) * 8);
        half8 b11 = *(const half8*)(bp + (3 * 64 + L) * 8);
        _Float16 f = sF[rowi * 136 + r];
        half8 fs;
#pragma unroll
        for (int k = 0; k < 8; ++k) fs[k] = f;
        half8 a0 = fs * xf[0];
        half8 a1 = fs * xf[1];
        oacc[0] = MFMA16(a0, b00, oacc[0]);
        oacc[0] = MFMA16(a1, b10, oacc[0]);
        oacc[1] = MFMA16(a0, b01, oacc[1]);
        oacc[1] = MFMA16(a1, b11, oacc[1]);
    }

    // W0 term: rules rh*64 + sg*32, sg in {0,1}
#pragma unroll
    for (int sg = 0; sg < 2; ++sg) {
        int s = 2 * rh + sg;
        half8 a = *(const half8*)(sF + rowi * 136 + s * 32 + q * 8);
        half8 b0 = *(const half8*)(W0f + ((s * 2 + 0) * 64 + L) * 8);
        half8 b1 = *(const half8*)(W0f + ((s * 2 + 1) * 64 + L) * 8);
        oacc[0] = MFMA16(a, b0, oacc[0]);
        oacc[1] = MFMA16(a, b1, oacc[1]);
    }

    // ---- E: cross-half reduce + bias + store ----
    float* sR = sU;  // [2 mt][16 rows][33 cols]
    if (rh == 1) {
#pragma unroll
        for (int ntl = 0; ntl < 2; ++ntl)
#pragma unroll
            for (int reg = 0; reg < 4; ++reg)
                sR[(mt * 16 + q * 4 + reg) * 33 + ntl * 16 + m] = oacc[ntl][reg];
    }
    __syncthreads();
    if (rh == 0) {
        float b0 = bias[m];
        float b1 = bias[16 + m];
#pragma unroll
        for (int ntl = 0; ntl < 2; ++ntl) {
            float bb = ntl ? b1 : b0;
#pragma unroll
            for (int reg = 0; reg < 4; ++reg) {
                int rloc = mt * 16 + q * 4 + reg;
                int col = ntl * 16 + m;
                float vv = oacc[ntl][reg] + sR[rloc * 33 + col] + bb;
                out[(row0 + rloc) * 32 + col] = vv;
            }
        }
    }
}

extern "C" void kernel_launch(void* const* d_in, const int* in_sizes, int n_in,
                              void* d_out, int out_size, void* d_ws, size_t ws_size,
                              hipStream_t stream) {
    const float* X = (const float*)d_in[0];
    const float* centers = (const float*)d_in[1];
    const float* sigmas = (const float*)d_in[2];
    const float* W = (const float*)d_in[3];
    const float* b = (const float*)d_in[4];
    float* outp = (float*)d_out;               // [16384*32]
    float* frs_out = outp + NROWS * 32;        // [16384*128]
    if (ws_size < (size_t)WS_BYTES_NEEDED) return;
    _Float16* wsh = (_Float16*)d_ws;
    float* kvec = (float*)((char*)d_ws + KVEC_BYTE_OFF);

    prep_kernel<<<137, 256, 0, stream>>>(centers, sigmas, W, wsh, kvec);
    main_fused<<<NROWS / 32, 256, 0, stream>>>(X, b, wsh, kvec, outp, frs_out);
}

// Round 5
// 91.037 us; speedup vs baseline: 1.1603x; 1.0199x over previous
//
#include <hip/hip_runtime.h>

// HTSK fuzzy-TSK fused pipeline for MI355X (gfx950), round 5.
// prep: build f16 MFMA B-fragments for W, W0, split-f16 logits B-matrix; kvec
//       in a tiny second kernel (runs concurrently-ish, negligible).
// main: fused logits->softmax->GEMM; phase D rule-quarter per wave (disjoint
//       Wfrag streams, depth-1 prefetch), one-barrier 4-way reduce epilogue.
// d_out = [out fp32 16384*32][frs fp32 16384*128]

#define H_CONST 0.5f
#define EPS_CONST 1e-8f
#define NROWS 16384
#define NRULES 128
#define WCOLS 8320

typedef _Float16 half8 __attribute__((ext_vector_type(8)));
typedef float floatx4 __attribute__((ext_vector_type(4)));

#define MFMA16(a, b, c) __builtin_amdgcn_mfma_f32_16x16x32_f16((a), (b), (c), 0, 0, 0)

// ws layout (halves):
//   Wfrag : [r 128][s 2][nt 2][L 64][j 8]  = 262144 halves
//   W0frag: [s 4][nt 2][L 64][j 8]         =   4096 halves
//   Bmat  : [s 12][nt 8][L 64][j 8]        =  49152 halves
//   Kvec  : fp32[128] at byte offset 630784
#define WFRAG_OFF 0
#define W0FRAG_OFF 262144
#define BMAT_OFF   (262144 + 4096)
#define KVEC_BYTE_OFF 630784
#define WS_BYTES_NEEDED (630784 + 512)

// ---------------------------------------------------------------------------
// prep: 137 blocks x 256 (validated rounds 2-4; kvec tail moved out).
// ---------------------------------------------------------------------------
__global__ __launch_bounds__(256) void prep_kernel(
    const float* __restrict__ centers, const float* __restrict__ sigmas,
    const float* __restrict__ W, _Float16* __restrict__ wsh)
{
    __shared__ float sBuf[32 * 68];
    const int t = threadIdx.x;
    const int b = blockIdx.x;

    if (b < 128) {
        const int r = b;
        {
            int o = t >> 3, seg = t & 7;
            const float* g = W + o * WCOLS + r * 64 + seg * 8;
            floatx4 a = *(const floatx4*)g;
            floatx4 c = *(const floatx4*)(g + 4);
            *(floatx4*)(sBuf + o * 68 + seg * 8) = a;
            *(floatx4*)(sBuf + o * 68 + seg * 8 + 4) = c;
        }
        __syncthreads();
        {
            int L = t & 63, nt = (t >> 6) & 1, s = t >> 7;
            int o = nt * 16 + (L & 15);
            int ib = s * 32 + ((L >> 4) & 3) * 8;
            floatx4 fa = *(const floatx4*)(sBuf + o * 68 + ib);
            floatx4 fb = *(const floatx4*)(sBuf + o * 68 + ib + 4);
            half8 h;
#pragma unroll
            for (int k = 0; k < 8; ++k) h[k] = (_Float16)((k < 4) ? fa[k & 3] : fb[k & 3]);
            *(half8*)(wsh + WFRAG_OFF + r * 2048 + t * 8) = h;
        }
    } else if (b < 136) {
        const int nt = b - 128;
        float* sS = sBuf;
        float* sC = sBuf + 1088;
        {
            int i = t >> 2, c0 = (t & 3) * 4;
            floatx4 sg4 = *(const floatx4*)(sigmas + i * NRULES + nt * 16 + c0);
            floatx4 ct4 = *(const floatx4*)(centers + i * NRULES + nt * 16 + c0);
#pragma unroll
            for (int k = 0; k < 4; ++k) { sS[i * 17 + c0 + k] = sg4[k]; sC[i * 17 + c0 + k] = ct4[k]; }
        }
        __syncthreads();
#pragma unroll
        for (int kk = 0; kk < 3; ++kk) {
            int unit = t + kk * 256;
            int s = unit >> 6, L = unit & 63;
            int q = (L >> 4) & 3, nl = L & 15;
            int g = s >> 1;
            int i0 = (s & 1) * 32 + q * 8;
            half8 h;
#pragma unroll
            for (int j = 0; j < 8; ++j) {
                int i = i0 + j;
                float sg = sS[i * 17 + nl];
                float S = H_CONST / (sg * sg) + EPS_CONST;
                float c = sC[i * 17 + nl];
                float CS2 = 2.0f * c * S;
                _Float16 v;
                if (g == 0 || g == 2) v = -(_Float16)S;
                else if (g == 1) { _Float16 sh = (_Float16)S; v = -(_Float16)(S - (float)sh); }
                else if (g == 3 || g == 5) v = (_Float16)CS2;
                else { _Float16 ch = (_Float16)CS2; v = (_Float16)(CS2 - (float)ch); }
                h[j] = v;
            }
            *(half8*)(wsh + BMAT_OFF + ((s * 8 + nt) * 64 + L) * 8) = h;
        }
    } else {
#pragma unroll
        for (int kk = 0; kk < 2; ++kk) {
            int unit = t + kk * 256;
            int s = unit >> 7, nt = (unit >> 6) & 1, L = unit & 63;
            int q = (L >> 4) & 3;
            int o = nt * 16 + (L & 15);
            half8 h;
#pragma unroll
            for (int j = 0; j < 8; ++j) {
                int r = s * 32 + q * 8 + j;
                h[j] = (_Float16)W[o * WCOLS + 8192 + r];
            }
            *(half8*)(wsh + W0FRAG_OFF + ((s * 2 + nt) * 64 + L) * 8) = h;
        }
    }
}

// kvec: one tiny block (runs alongside prep's tail; negligible cost)
__global__ __launch_bounds__(128) void prep_kvec(
    const float* __restrict__ centers, const float* __restrict__ sigmas,
    float* __restrict__ kvec)
{
    int r = threadIdx.x;
    float acc = 0.f;
#pragma unroll 8
    for (int i = 0; i < 64; ++i) {
        float sg = sigmas[i * NRULES + r];
        float S = H_CONST / (sg * sg) + EPS_CONST;
        float c = centers[i * NRULES + r];
        acc += c * c * S;
    }
    kvec[r] = acc;
}

// ---------------------------------------------------------------------------
// main (fused): 512 blocks x 256, 32 rows/block.
//   A: stage X splits -> LDS
//   B: logits MFMA (split-f16)
//   C: softmax -> frs fp32 global + frs f16 LDS
//   D: GEMM, wave w = rule-quarter (32 rules), both m-tiles; depth-1 prefetch
//   E: one-barrier 4-way LDS reduce + bias + store
// ---------------------------------------------------------------------------
__global__ __launch_bounds__(256) void main_fused(
    const float* __restrict__ X, const float* __restrict__ bias,
    const _Float16* __restrict__ wsh, const float* __restrict__ kvec,
    float* __restrict__ out, float* __restrict__ frs_out)
{
    __shared__ _Float16 sXh[32 * 64];
    __shared__ _Float16 sXl[32 * 64];
    __shared__ _Float16 sX2h[32 * 64];
    __shared__ _Float16 sX2l[32 * 64];
    __shared__ _Float16 sF[32 * 136];   // frs f16, row stride 136
    __shared__ float sU[4608];          // logits (stride 132) / sP[4][32][36]

    const int t = threadIdx.x;
    const int w = t >> 6;
    const int L = t & 63;
    const int m = L & 15;
    const int q = L >> 4;
    const int row0 = blockIdx.x * 32;

    // ---- A ----
    {
        int row = t >> 3, uc = t & 7;
        const float* gx = X + (row0 + row) * 64 + uc * 8;
        floatx4 xa = *(const floatx4*)gx;
        floatx4 xb = *(const floatx4*)(gx + 4);
        int base = row * 64 + (uc ^ (row & 7)) * 8;
        half8 vh, vl, v2h, v2l;
#pragma unroll
        for (int k = 0; k < 8; ++k) {
            float x = (k < 4) ? xa[k & 3] : xb[k & 3];
            _Float16 xh = (_Float16)x;
            _Float16 xl2 = (_Float16)(x - (float)xh);
            float x2 = x * x;
            _Float16 x2h = (_Float16)x2;
            _Float16 x2l = (_Float16)(x2 - (float)x2h);
            vh[k] = xh; vl[k] = xl2; v2h[k] = x2h; v2l[k] = x2l;
        }
        *(half8*)(sXh + base) = vh;
        *(half8*)(sXl + base) = vl;
        *(half8*)(sX2h + base) = v2h;
        *(half8*)(sX2l + base) = v2l;
    }
    __syncthreads();

    // ---- B ----
    floatx4 lacc[2][2];
#pragma unroll
    for (int mt = 0; mt < 2; ++mt)
#pragma unroll
        for (int n = 0; n < 2; ++n) lacc[mt][n] = (floatx4){0.f, 0.f, 0.f, 0.f};

    const _Float16* Bm = wsh + BMAT_OFF;
#pragma unroll
    for (int s = 0; s < 12; ++s) {
        const _Float16* arr = (s < 4) ? sX2h : (s < 6) ? sX2l : (s < 10) ? sXh : sXl;
        int phys = (((s & 1) << 2) | q) ^ (m & 7);
        half8 b0 = *(const half8*)(Bm + ((s * 8 + 2 * w + 0) * 64 + L) * 8);
        half8 b1 = *(const half8*)(Bm + ((s * 8 + 2 * w + 1) * 64 + L) * 8);
#pragma unroll
        for (int mt = 0; mt < 2; ++mt) {
            half8 a = *(const half8*)(arr + (mt * 16 + m) * 64 + phys * 8);
            lacc[mt][0] = MFMA16(a, b0, lacc[mt][0]);
            lacc[mt][1] = MFMA16(a, b1, lacc[mt][1]);
        }
    }
    float kv0 = kvec[(2 * w + 0) * 16 + m];
    float kv1 = kvec[(2 * w + 1) * 16 + m];

#pragma unroll
    for (int mt = 0; mt < 2; ++mt)
#pragma unroll
        for (int ntl = 0; ntl < 2; ++ntl)
#pragma unroll
            for (int reg = 0; reg < 4; ++reg) {
                int rl = mt * 16 + q * 4 + reg;
                int col = (2 * w + ntl) * 16 + m;
                sU[rl * 132 + col] = lacc[mt][ntl][reg] - (ntl ? kv1 : kv0);
            }
    __syncthreads();

    // ---- C ----
    {
        int row = t >> 3, l8 = t & 7;
        int base = row * 132 + l8 * 16;
        float v[16];
        float mx = -1e30f;
#pragma unroll
        for (int k = 0; k < 16; ++k) { v[k] = sU[base + k]; mx = fmaxf(mx, v[k]); }
        mx = fmaxf(mx, __shfl_xor(mx, 1));
        mx = fmaxf(mx, __shfl_xor(mx, 2));
        mx = fmaxf(mx, __shfl_xor(mx, 4));
        float sum = 0.f;
#pragma unroll
        for (int k = 0; k < 16; ++k) { v[k] = __expf(v[k] - mx); sum += v[k]; }
        sum += __shfl_xor(sum, 1);
        sum += __shfl_xor(sum, 2);
        sum += __shfl_xor(sum, 4);
        float inv = 1.0f / sum;
        float* gf = frs_out + (row0 + row) * 128 + l8 * 16;
        half8 h0, h1;
#pragma unroll
        for (int c = 0; c < 4; ++c) {
            floatx4 o4;
#pragma unroll
            for (int k = 0; k < 4; ++k) {
                float f = v[c * 4 + k] * inv;
                o4[k] = f;
                if (c < 2) h0[c * 4 + k] = (_Float16)f; else h1[(c - 2) * 4 + k] = (_Float16)f;
            }
            *(floatx4*)(gf + c * 4) = o4;
        }
        *(half8*)(sF + row * 136 + l8 * 16) = h0;
        *(half8*)(sF + row * 136 + l8 * 16 + 8) = h1;
    }
    __syncthreads();

    // ---- D ----
    const int rq = w;
    const int r0 = rq * 32;
    const _Float16* Wf = wsh + WFRAG_OFF;
    const _Float16* W0f = wsh + W0FRAG_OFF;

#define LDW(r, slot) (*(const half8*)(Wf + (r) * 2048 + ((slot) * 64 + L) * 8))

    half8 xf[2][2];
#pragma unroll
    for (int mt = 0; mt < 2; ++mt)
#pragma unroll
        for (int s = 0; s < 2; ++s) {
            int phys = ((s << 2) | q) ^ (m & 7);
            xf[mt][s] = *(const half8*)(sXh + (mt * 16 + m) * 64 + phys * 8);
        }

    floatx4 oacc[2][2];
#pragma unroll
    for (int mt = 0; mt < 2; ++mt)
#pragma unroll
        for (int n = 0; n < 2; ++n) oacc[mt][n] = (floatx4){0.f, 0.f, 0.f, 0.f};

    half8 b00 = LDW(r0, 0), b01 = LDW(r0, 1), b10 = LDW(r0, 2), b11 = LDW(r0, 3);

#pragma unroll
    for (int rg = 0; rg < 4; ++rg) {
        half8 fv0 = *(const half8*)(sF + (0 * 16 + m) * 136 + r0 + rg * 8);
        half8 fv1 = *(const half8*)(sF + (1 * 16 + m) * 136 + r0 + rg * 8);
#pragma unroll
        for (int rr2 = 0; rr2 < 8; ++rr2) {
            half8 c00 = b00, c01 = b01, c10 = b10, c11 = b11;
            if (rg * 8 + rr2 < 31) {
                int rn = r0 + rg * 8 + rr2 + 1;
                b00 = LDW(rn, 0); b01 = LDW(rn, 1); b10 = LDW(rn, 2); b11 = LDW(rn, 3);
            }
            _Float16 f0 = fv0[rr2], f1 = fv1[rr2];
            half8 fs0, fs1;
#pragma unroll
            for (int k = 0; k < 8; ++k) { fs0[k] = f0; fs1[k] = f1; }
            half8 a00 = fs0 * xf[0][0];
            half8 a01 = fs0 * xf[0][1];
            half8 a10 = fs1 * xf[1][0];
            half8 a11 = fs1 * xf[1][1];
            oacc[0][0] = MFMA16(a00, c00, oacc[0][0]);
            oacc[0][0] = MFMA16(a01, c10, oacc[0][0]);
            oacc[0][1] = MFMA16(a00, c01, oacc[0][1]);
            oacc[0][1] = MFMA16(a01, c11, oacc[0][1]);
            oacc[1][0] = MFMA16(a10, c00, oacc[1][0]);
            oacc[1][0] = MFMA16(a11, c10, oacc[1][0]);
            oacc[1][1] = MFMA16(a10, c01, oacc[1][1]);
            oacc[1][1] = MFMA16(a11, c11, oacc[1][1]);
        }
    }

    {
        half8 wb0 = *(const half8*)(W0f + ((rq * 2 + 0) * 64 + L) * 8);
        half8 wb1 = *(const half8*)(W0f + ((rq * 2 + 1) * 64 + L) * 8);
#pragma unroll
        for (int mt = 0; mt < 2; ++mt) {
            half8 a = *(const half8*)(sF + (mt * 16 + m) * 136 + rq * 32 + q * 8);
            oacc[mt][0] = MFMA16(a, wb0, oacc[mt][0]);
            oacc[mt][1] = MFMA16(a, wb1, oacc[mt][1]);
        }
    }

#pragma unroll
    for (int mt = 0; mt < 2; ++mt)
#pragma unroll
        for (int ntl = 0; ntl < 2; ++ntl)
#pragma unroll
            for (int reg = 0; reg < 4; ++reg)
                sU[w * 1152 + (mt * 16 + q * 4 + reg) * 36 + ntl * 16 + m] = oacc[mt][ntl][reg];
    __syncthreads();

    // ---- E ----
    {
        int row = t >> 3, col0 = (t & 7) * 4;
        floatx4 acc = *(const floatx4*)(sU + 0 * 1152 + row * 36 + col0);
        acc += *(const floatx4*)(sU + 1 * 1152 + row * 36 + col0);
        acc += *(const floatx4*)(sU + 2 * 1152 + row * 36 + col0);
        acc += *(const floatx4*)(sU + 3 * 1152 + row * 36 + col0);
        acc += *(const floatx4*)(bias + col0);
        *(floatx4*)(out + (row0 + row) * 32 + col0) = acc;
    }
#undef LDW
}

extern "C" void kernel_launch(void* const* d_in, const int* in_sizes, int n_in,
                              void* d_out, int out_size, void* d_ws, size_t ws_size,
                              hipStream_t stream) {
    const float* X = (const float*)d_in[0];
    const float* centers = (const float*)d_in[1];
    const float* sigmas = (const float*)d_in[2];
    const float* W = (const float*)d_in[3];
    const float* b = (const float*)d_in[4];
    float* outp = (float*)d_out;               // [16384*32]
    float* frs_out = outp + NROWS * 32;        // [16384*128]
    if (ws_size < (size_t)WS_BYTES_NEEDED) return;
    _Float16* wsh = (_Float16*)d_ws;
    float* kvec = (float*)((char*)d_ws + KVEC_BYTE_OFF);

    prep_kernel<<<137, 256, 0, stream>>>(centers, sigmas, W, wsh);
    prep_kvec<<<1, 128, 0, stream>>>(centers, sigmas, kvec);
    main_fused<<<NROWS / 32, 256, 0, stream>>>(X, b, wsh, kvec, outp, frs_out);
}